// Round 1
// baseline (592.479 us; speedup 1.0000x reference)
//
#include <hip/hip_runtime.h>
#include <stdint.h>

#define B_ 2
#define M_ 4096
#define N_ 4096
#define K_ 4096
#define KW 64   // u64 words per K-row (K/64)
#define KC 16   // K-chunk in words
#define TM 128
#define TN 128

// Pack sign bits: each wave handles 256 consecutive floats -> 4 u64 words.
// Bit order within a 256-float group is a fixed permutation (bit l of word w
// = sign of element 4*l + w); identical for x and y, so dot products match.
__global__ __launch_bounds__(256) void pack_signs(const float* __restrict__ in,
                                                  unsigned long long* __restrict__ out,
                                                  int ngroups) {
    int gid   = blockIdx.x * blockDim.x + threadIdx.x;
    int wave  = gid >> 6;
    int lane  = threadIdx.x & 63;
    int nwaves = (gridDim.x * blockDim.x) >> 6;
    for (int g = wave; g < ngroups; g += nwaves) {
        float4 v = *(const float4*)(in + (size_t)g * 256 + lane * 4);
        unsigned long long m0 = __ballot(v.x >= 0.0f);
        unsigned long long m1 = __ballot(v.y >= 0.0f);
        unsigned long long m2 = __ballot(v.z >= 0.0f);
        unsigned long long m3 = __ballot(v.w >= 0.0f);
        if (lane == 0) {
            ulonglong2* o = (ulonglong2*)(out + (size_t)g * 4);
            o[0] = make_ulonglong2(m0, m1);
            o[1] = make_ulonglong2(m2, m3);
        }
    }
}

// Binary GEMM: C[b][m][n] = (K - 2*popcount(xor)) * scale
// Block: 128x128 tile, 256 threads, each thread 8x8 outputs at
// rows ty+16i, cols tx+16j  (strided -> conflict-free LDS reads).
__global__ __launch_bounds__(256) void bgemm(const unsigned long long* __restrict__ pa,
                                             const unsigned long long* __restrict__ pb,
                                             float* __restrict__ out,
                                             const float* __restrict__ xclip,
                                             const float* __restrict__ yclip) {
    __shared__ unsigned long long As[KC][TM];  // [kw][row], transposed
    __shared__ unsigned long long Bs[KC][TN];

    const int b  = blockIdx.z;
    const int m0 = blockIdx.x * TM;
    const int n0 = blockIdx.y * TN;
    const int t  = threadIdx.x;
    const int tx = t & 15;
    const int ty = t >> 4;

    const unsigned long long* arow = pa + ((size_t)b * M_ + m0) * KW;
    const unsigned long long* brow = pb + ((size_t)b * N_ + n0) * KW;

    unsigned acc[8][8] = {};

    for (int kc = 0; kc < KW; kc += KC) {
        // Stage 128 rows x 16 words per tile; 1024 u64x2 pairs, 4 per thread.
#pragma unroll
        for (int i = 0; i < 4; ++i) {
            int p = t + 256 * i;
            int r = p >> 3;
            int c = (p & 7) * 2;
            ulonglong2 va = *(const ulonglong2*)(arow + (size_t)r * KW + kc + c);
            As[c][r] = va.x;
            As[c + 1][r] = va.y;
            ulonglong2 vb = *(const ulonglong2*)(brow + (size_t)r * KW + kc + c);
            Bs[c][r] = vb.x;
            Bs[c + 1][r] = vb.y;
        }
        __syncthreads();

#pragma unroll
        for (int kw = 0; kw < KC; ++kw) {
            unsigned long long a[8], bv[8];
#pragma unroll
            for (int i = 0; i < 8; ++i) a[i] = As[kw][ty + 16 * i];
#pragma unroll
            for (int j = 0; j < 8; ++j) bv[j] = Bs[kw][tx + 16 * j];
#pragma unroll
            for (int i = 0; i < 8; ++i)
#pragma unroll
                for (int j = 0; j < 8; ++j)
                    acc[i][j] += (unsigned)__popcll(a[i] ^ bv[j]);
        }
        __syncthreads();
    }

    const float scale = xclip[0] * yclip[0];
#pragma unroll
    for (int i = 0; i < 8; ++i) {
        int m = m0 + ty + 16 * i;
        float* orow = out + ((size_t)b * M_ + m) * (size_t)N_ + n0;
#pragma unroll
        for (int j = 0; j < 8; ++j) {
            int n = tx + 16 * j;
            orow[n] = scale * (float)(K_ - 2 * (int)acc[i][j]);
        }
    }
}

extern "C" void kernel_launch(void* const* d_in, const int* in_sizes, int n_in,
                              void* d_out, int out_size, void* d_ws, size_t ws_size,
                              hipStream_t stream) {
    const float* x     = (const float*)d_in[0];
    const float* y     = (const float*)d_in[1];
    const float* xclip = (const float*)d_in[2];
    const float* yclip = (const float*)d_in[3];
    float* out = (float*)d_out;

    unsigned long long* pa = (unsigned long long*)d_ws;            // [B][M][KW] = 4 MB
    unsigned long long* pb = pa + (size_t)B_ * M_ * KW;            // [B][N][KW] = 4 MB

    const int ngroups = B_ * M_ * K_ / 256;  // 131072 (same for y)
    hipLaunchKernelGGL(pack_signs, dim3(2048), dim3(256), 0, stream, x, pa, ngroups);
    hipLaunchKernelGGL(pack_signs, dim3(2048), dim3(256), 0, stream, y, pb, ngroups);

    dim3 grid(M_ / TM, N_ / TN, B_);
    hipLaunchKernelGGL(bgemm, grid, dim3(256), 0, stream, pa, pb, out, xclip, yclip);
}